// Round 1
// baseline (464.290 us; speedup 1.0000x reference)
//
#include <hip/hip_runtime.h>
#include <hip/hip_bf16.h>

#define N_ATOMS 200000
#define N_NBR 10
#define N_MOLS 8000
#define HID 128
#define FDIM 151
#define FEAT 200
#define DFF 512
#define FFN_H 256
#define TASKS 12
#define KX 279      // FDIM + HID
#define K1P 288     // KX padded to multiple of 32
#define XS 296      // LDS stride (bf16 elems) for X tile
#define HS 520      // LDS stride (bf16 elems) for H tile
#define FS 132      // LDS stride (f32 elems) for ffn tile
#define KM 328      // HID + FEAT
#define K3 352      // KM padded to multiple of 32
#define MS 360      // LDS stride for molcat tile
#define MT 32       // atoms kernel M-tile

typedef __hip_bfloat16 bf16;
typedef __attribute__((ext_vector_type(8))) __bf16 bf16x8;
typedef __attribute__((ext_vector_type(4))) float f32x4;

__device__ __forceinline__ float bf2f(bf16 x) { return __bfloat162float(x); }

// ---------------- weight prep: transpose + bf16 + K-pad ----------------
__global__ void prep_weights_kernel(const float* __restrict__ W1,
                                    const float* __restrict__ W2,
                                    const float* __restrict__ Wf1,
                                    bf16* __restrict__ W1bT,
                                    bf16* __restrict__ W2bT,
                                    bf16* __restrict__ Wf1bT) {
  int idx = blockIdx.x * 256 + threadIdx.x;
  if (idx < DFF * K1P) {                       // W1bT[n][k] = W1[k][n], 512x288
    int n = idx / K1P, k = idx - n * K1P;
    float v = (k < KX) ? W1[k * DFF + n] : 0.f;
    W1bT[idx] = __float2bfloat16(v);
    return;
  }
  idx -= DFF * K1P;
  if (idx < HID * DFF) {                       // W2bT[n][k] = W2[k][n], 128x512
    int n = idx / DFF, k = idx - n * DFF;
    W2bT[idx] = __float2bfloat16(W2[k * HID + n]);
    return;
  }
  idx -= HID * DFF;
  if (idx < FFN_H * K3) {                      // Wf1bT[n][k] = Wf1[k][n], 256x352
    int n = idx / K3, k = idx - n * K3;
    float v = (k < KM) ? Wf1[k * FFN_H + n] : 0.f;
    Wf1bT[idx] = __float2bfloat16(v);
  }
}

// ---------------- atom_output f32 -> bf16 (halves gather traffic) ----------------
__global__ void conv_ao_kernel(const float* __restrict__ ao, bf16* __restrict__ ao16) {
  const int idx = blockIdx.x * 256 + threadIdx.x;   // exactly N_ATOMS*HID/8 threads
  const float4 v0 = *(const float4*)&ao[(size_t)idx * 8];
  const float4 v1 = *(const float4*)&ao[(size_t)idx * 8 + 4];
  union { bf16 h[8]; uint4 u; } pk;
  pk.h[0] = __float2bfloat16(v0.x); pk.h[1] = __float2bfloat16(v0.y);
  pk.h[2] = __float2bfloat16(v0.z); pk.h[3] = __float2bfloat16(v0.w);
  pk.h[4] = __float2bfloat16(v1.x); pk.h[5] = __float2bfloat16(v1.y);
  pk.h[6] = __float2bfloat16(v1.z); pk.h[7] = __float2bfloat16(v1.w);
  *(uint4*)&ao16[(size_t)idx * 8] = pk.u;
}

// ---------------- fused gather + GEMM1(relu) + GEMM2 + LayerNorm ----------------
__global__ __launch_bounds__(512)
void atoms_kernel(const float* __restrict__ atom_output,
                  const bf16* __restrict__ ao16, const int use16,
                  const float* __restrict__ f_atoms,
                  const int* __restrict__ a2a,
                  const bf16* __restrict__ W1bT,
                  const float* __restrict__ b1,
                  const bf16* __restrict__ W2bT,
                  const float* __restrict__ b2,
                  const float* __restrict__ gamma,
                  const float* __restrict__ beta,
                  bf16* __restrict__ atom_emb) {
  __shared__ char smem[MT * XS * 2 + MT * HS * 2];   // 18944 + 33280 = 52224 B
  bf16* Xs = (bf16*)smem;                 // [MT][XS]
  bf16* Hs = (bf16*)(smem + MT * XS * 2); // [MT][HS]
  float* Fs = (float*)smem;               // [MT][FS] aliases Xs (dead after GEMM1)

  const int tid = threadIdx.x;
  const int m0 = blockIdx.x * MT;
  const int lane = tid & 63;
  const int w = tid >> 6;
  const int lr = lane & 15;
  const int lk = lane >> 4;

  // stage f_atoms -> Xs[:, 0:151]
  for (int idx = tid; idx < MT * FDIM; idx += 512) {
    int r = idx / FDIM, c = idx - r * FDIM;
    Xs[r * XS + c] = __float2bfloat16(f_atoms[(size_t)(m0 + r) * FDIM + c]);
  }
  // zero K-pad cols 279..287
  if (tid < MT * (K1P - KX)) {
    int r = tid / (K1P - KX), c = tid - r * (K1P - KX);
    Xs[r * XS + KX + c] = __float2bfloat16(0.f);
  }
  // neighbor gather-sum -> Xs[:, 151:279]
  for (int idx = tid; idx < MT * HID; idx += 512) {
    int r = idx >> 7, c = idx & (HID - 1);
    const int arow = m0 + r;
    float s = 0.f;
    if (use16) {
#pragma unroll
      for (int j = 0; j < N_NBR; ++j) {
        int nb = a2a[arow * N_NBR + j];
        s += bf2f(ao16[(size_t)nb * HID + c]);
      }
    } else {
#pragma unroll
      for (int j = 0; j < N_NBR; ++j) {
        int nb = a2a[arow * N_NBR + j];
        s += atom_output[(size_t)nb * HID + c];
      }
    }
    Xs[r * XS + FDIM + c] = __float2bfloat16(s);
  }
  __syncthreads();

  // GEMM1: Xs[MT x 288] @ W1[288 x 512] -> relu -> Hs (bf16)
  {
    const int wn = w * 64;
    f32x4 acc[2][4];
#pragma unroll
    for (int mi = 0; mi < 2; ++mi)
#pragma unroll
      for (int ni = 0; ni < 4; ++ni) acc[mi][ni] = (f32x4)0.f;
    for (int kk = 0; kk < K1P / 32; ++kk) {
      bf16x8 a[2], b[4];
#pragma unroll
      for (int mi = 0; mi < 2; ++mi)
        a[mi] = *(const bf16x8*)&Xs[(mi * 16 + lr) * XS + kk * 32 + lk * 8];
#pragma unroll
      for (int ni = 0; ni < 4; ++ni)
        b[ni] = *(const bf16x8*)&W1bT[(size_t)(wn + ni * 16 + lr) * K1P + kk * 32 + lk * 8];
#pragma unroll
      for (int mi = 0; mi < 2; ++mi)
#pragma unroll
        for (int ni = 0; ni < 4; ++ni)
          acc[mi][ni] = __builtin_amdgcn_mfma_f32_16x16x32_bf16(a[mi], b[ni], acc[mi][ni], 0, 0, 0);
    }
#pragma unroll
    for (int ni = 0; ni < 4; ++ni) {
      const int n = wn + ni * 16 + lr;
      const float bias = b1[n];
#pragma unroll
      for (int mi = 0; mi < 2; ++mi)
#pragma unroll
        for (int r = 0; r < 4; ++r) {
          const int row = mi * 16 + lk * 4 + r;
          float h = acc[mi][ni][r] + bias;
          Hs[row * HS + n] = __float2bfloat16(h > 0.f ? h : 0.f);
        }
    }
  }
  __syncthreads();

  // GEMM2: Hs[MT x 512] @ W2[512 x 128] -> +b2 -> Fs (f32)
  {
    const int n2 = w * 16 + lr;
    f32x4 acc2[2];
    acc2[0] = (f32x4)0.f; acc2[1] = (f32x4)0.f;
    for (int kk = 0; kk < DFF / 32; ++kk) {
      bf16x8 bfrag = *(const bf16x8*)&W2bT[(size_t)n2 * DFF + kk * 32 + lk * 8];
#pragma unroll
      for (int mi = 0; mi < 2; ++mi) {
        bf16x8 afrag = *(const bf16x8*)&Hs[(mi * 16 + lr) * HS + kk * 32 + lk * 8];
        acc2[mi] = __builtin_amdgcn_mfma_f32_16x16x32_bf16(afrag, bfrag, acc2[mi], 0, 0, 0);
      }
    }
    const float bias2 = b2[n2];
#pragma unroll
    for (int mi = 0; mi < 2; ++mi)
#pragma unroll
      for (int r = 0; r < 4; ++r) {
        const int row = mi * 16 + lk * 4 + r;
        Fs[row * FS + n2] = acc2[mi][r] + bias2;
      }
  }
  __syncthreads();

  // LayerNorm each of MT rows (one wave handles MT/8 rows), write atom_emb bf16
  {
#pragma unroll
    for (int i = 0; i < MT / 8; ++i) {
      const int row = w * (MT / 8) + i;
      float x0 = Fs[row * FS + lane];
      float x1 = Fs[row * FS + 64 + lane];
      float s = x0 + x1;
      float q = x0 * x0 + x1 * x1;
#pragma unroll
      for (int off = 32; off > 0; off >>= 1) {
        s += __shfl_xor(s, off);
        q += __shfl_xor(q, off);
      }
      const float mu = s * (1.f / 128.f);
      const float var = q * (1.f / 128.f) - mu * mu;
      const float rs = rsqrtf(var + 1e-6f);
      const int atom = m0 + row;
      atom_emb[(size_t)atom * HID + lane] =
          __float2bfloat16(gamma[lane] * ((x0 - mu) * rs) + beta[lane]);
      atom_emb[(size_t)atom * HID + 64 + lane] =
          __float2bfloat16(gamma[64 + lane] * ((x1 - mu) * rs) + beta[64 + lane]);
    }
  }
}

// ---------------- segment mean + concat features -> mol_cat bf16 (K-padded) ----------------
__global__ void mol_kernel(const bf16* __restrict__ atom_emb,
                           const float* __restrict__ features,
                           const int* __restrict__ a_scope,
                           bf16* __restrict__ mol_cat) {
  const int m = blockIdx.x;
  const int tid = threadIdx.x;   // 128 threads
  const int start = a_scope[2 * m];
  const int size  = a_scope[2 * m + 1];
  float s = 0.f;
  for (int a = start; a < start + size; ++a)
    s += bf2f(atom_emb[(size_t)a * HID + tid]);
  mol_cat[(size_t)m * K3 + tid] = __float2bfloat16(s / (float)size);
  for (int c = tid; c < FEAT; c += 128)
    mol_cat[(size_t)m * K3 + HID + c] = __float2bfloat16(features[(size_t)m * FEAT + c]);
  for (int c = KM + tid; c < K3; c += 128)
    mol_cat[(size_t)m * K3 + c] = __float2bfloat16(0.f);
}

// ---------------- mol FFN layer 1: [8000 x 352] @ [352 x 256] relu ----------------
__global__ __launch_bounds__(512)
void molffn1_kernel(const bf16* __restrict__ mol_cat,
                    const bf16* __restrict__ Wf1bT,
                    const float* __restrict__ bf1,
                    bf16* __restrict__ Hf) {
  __shared__ bf16 As[64 * MS];   // 45 KB
  const int tid = threadIdx.x;
  const int m0 = blockIdx.x * 64;
  for (int idx = tid; idx < 64 * (K3 / 8); idx += 512) {
    int r = idx / (K3 / 8), qv = idx - r * (K3 / 8);
    *(uint4*)&As[r * MS + qv * 8] = *(const uint4*)&mol_cat[(size_t)(m0 + r) * K3 + qv * 8];
  }
  __syncthreads();
  const int lane = tid & 63, w = tid >> 6;
  const int lr = lane & 15, lk = lane >> 4;
  const int wn = w * 32;
  f32x4 acc[4][2];
#pragma unroll
  for (int mi = 0; mi < 4; ++mi)
#pragma unroll
    for (int ni = 0; ni < 2; ++ni) acc[mi][ni] = (f32x4)0.f;
  for (int kk = 0; kk < K3 / 32; ++kk) {
    bf16x8 a[4], b[2];
#pragma unroll
    for (int mi = 0; mi < 4; ++mi)
      a[mi] = *(const bf16x8*)&As[(mi * 16 + lr) * MS + kk * 32 + lk * 8];
#pragma unroll
    for (int ni = 0; ni < 2; ++ni)
      b[ni] = *(const bf16x8*)&Wf1bT[(size_t)(wn + ni * 16 + lr) * K3 + kk * 32 + lk * 8];
#pragma unroll
    for (int mi = 0; mi < 4; ++mi)
#pragma unroll
      for (int ni = 0; ni < 2; ++ni)
        acc[mi][ni] = __builtin_amdgcn_mfma_f32_16x16x32_bf16(a[mi], b[ni], acc[mi][ni], 0, 0, 0);
  }
#pragma unroll
  for (int ni = 0; ni < 2; ++ni) {
    const int n = wn + ni * 16 + lr;
    const float bias = bf1[n];
#pragma unroll
    for (int mi = 0; mi < 4; ++mi)
#pragma unroll
      for (int r = 0; r < 4; ++r) {
        const int row = mi * 16 + lk * 4 + r;
        float h = acc[mi][ni][r] + bias;
        Hf[(size_t)(m0 + row) * FFN_H + n] = __float2bfloat16(h > 0.f ? h : 0.f);
      }
  }
}

// ---------------- mol FFN layer 2: [8000 x 256] @ [256 x 12] ----------------
__global__ void molffn2_kernel(const bf16* __restrict__ Hf,
                               const float* __restrict__ Wf2,
                               const float* __restrict__ bias2,
                               float* __restrict__ out) {
  const int gid = blockIdx.x * 256 + threadIdx.x;  // exactly 96000 threads
  const int m = gid / TASKS, t = gid - m * TASKS;
  float s = bias2[t];
  for (int k = 0; k < FFN_H; ++k)
    s += bf2f(Hf[(size_t)m * FFN_H + k]) * Wf2[k * TASKS + t];
  out[gid] = s;
}

extern "C" void kernel_launch(void* const* d_in, const int* in_sizes, int n_in,
                              void* d_out, int out_size, void* d_ws, size_t ws_size,
                              hipStream_t stream) {
  const float* atom_output = (const float*)d_in[0];
  const float* f_atoms     = (const float*)d_in[1];
  const float* features    = (const float*)d_in[2];
  const int*   a2a         = (const int*)d_in[3];
  const int*   a_scope     = (const int*)d_in[4];
  const float* W1   = (const float*)d_in[5];
  const float* b1   = (const float*)d_in[6];
  const float* W2   = (const float*)d_in[7];
  const float* b2   = (const float*)d_in[8];
  const float* gamma = (const float*)d_in[9];
  const float* beta  = (const float*)d_in[10];
  const float* Wf1  = (const float*)d_in[11];
  const float* bf1  = (const float*)d_in[12];
  const float* Wf2  = (const float*)d_in[13];
  const float* bf2v = (const float*)d_in[14];
  float* out = (float*)d_out;

  char* ws = (char*)d_ws;
  size_t off = 0;
  bf16* W1bT  = (bf16*)(ws + off); off += (size_t)DFF * K1P * 2;     // 294912
  bf16* W2bT  = (bf16*)(ws + off); off += (size_t)HID * DFF * 2;     // 131072
  bf16* Wf1bT = (bf16*)(ws + off); off += (size_t)FFN_H * K3 * 2;    // 180224
  bf16* atom_emb = (bf16*)(ws + off); off += (size_t)N_ATOMS * HID * 2; // 51.2 MB
  bf16* mol_cat  = (bf16*)(ws + off); off += (size_t)N_MOLS * K3 * 2;   // 5.6 MB
  bf16* Hf       = (bf16*)(ws + off); off += (size_t)N_MOLS * FFN_H * 2;// 4.1 MB
  bf16* ao16     = (bf16*)(ws + off); off += (size_t)N_ATOMS * HID * 2; // 51.2 MB (optional)
  const int use16 = (ws_size >= off) ? 1 : 0;

  hipLaunchKernelGGL(prep_weights_kernel, dim3(1184), dim3(256), 0, stream,
                     W1, W2, Wf1, W1bT, W2bT, Wf1bT);
  if (use16)
    hipLaunchKernelGGL(conv_ao_kernel, dim3(N_ATOMS * HID / 8 / 256), dim3(256), 0, stream,
                       atom_output, ao16);
  hipLaunchKernelGGL(atoms_kernel, dim3(N_ATOMS / MT), dim3(512), 0, stream,
                     atom_output, ao16, use16, f_atoms, a2a,
                     W1bT, b1, W2bT, b2, gamma, beta, atom_emb);
  hipLaunchKernelGGL(mol_kernel, dim3(N_MOLS), dim3(128), 0, stream,
                     atom_emb, features, a_scope, mol_cat);
  hipLaunchKernelGGL(molffn1_kernel, dim3(N_MOLS / 64), dim3(512), 0, stream,
                     mol_cat, Wf1bT, bf1, Hf);
  hipLaunchKernelGGL(molffn2_kernel, dim3(N_MOLS * TASKS / 256), dim3(256), 0, stream,
                     Hf, Wf2, bf2v, out);
}

// Round 2
// 367.445 us; speedup vs baseline: 1.2636x; 1.2636x over previous
//
#include <hip/hip_runtime.h>
#include <hip/hip_bf16.h>

#define N_ATOMS 200000
#define N_NBR 10
#define N_MOLS 8000
#define HID 128
#define FDIM 151
#define FEAT 200
#define DFF 512
#define FFN_H 256
#define TASKS 12
#define KX 279      // FDIM + HID
#define K1P 288     // KX padded to multiple of 32
#define XS 296      // LDS stride (bf16 elems) for X tile
#define HS 520      // LDS stride (bf16 elems) for H tile
#define FS 132      // LDS stride (f32 elems) for ffn tile
#define KM 328      // HID + FEAT
#define K3 352      // KM padded to multiple of 32
#define MS 360      // LDS stride for molcat tile
#define MT 32       // atoms kernel M-tile

typedef __hip_bfloat16 bf16;
typedef __attribute__((ext_vector_type(8))) __bf16 bf16x8;
typedef __attribute__((ext_vector_type(4))) float f32x4;

__device__ __forceinline__ float bf2f(bf16 x) { return __bfloat162float(x); }
__device__ __forceinline__ float blo(unsigned w) { union { unsigned u; float f; } c; c.u = w << 16; return c.f; }
__device__ __forceinline__ float bhi(unsigned w) { union { unsigned u; float f; } c; c.u = w & 0xFFFF0000u; return c.f; }

// ---------------- weight prep: transpose + bf16 + K-pad (X layout: [aggr | f_atoms]) ----------------
__global__ void prep_weights_kernel(const float* __restrict__ W1,
                                    const float* __restrict__ W2,
                                    const float* __restrict__ Wf1,
                                    bf16* __restrict__ W1bT,
                                    bf16* __restrict__ W2bT,
                                    bf16* __restrict__ Wf1bT) {
  int idx = blockIdx.x * 256 + threadIdx.x;
  if (idx < DFF * K1P) {                       // W1bT[n][k'], 512x288; k'<128 -> aggr, else f_atoms
    int n = idx / K1P, k = idx - n * K1P;
    float v;
    if (k < HID)      v = W1[(size_t)(FDIM + k) * DFF + n];
    else if (k < KX)  v = W1[(size_t)(k - HID) * DFF + n];
    else              v = 0.f;
    W1bT[idx] = __float2bfloat16(v);
    return;
  }
  idx -= DFF * K1P;
  if (idx < HID * DFF) {                       // W2bT[n][k] = W2[k][n], 128x512
    int n = idx / DFF, k = idx - n * DFF;
    W2bT[idx] = __float2bfloat16(W2[(size_t)k * HID + n]);
    return;
  }
  idx -= HID * DFF;
  if (idx < FFN_H * K3) {                      // Wf1bT[n][k] = Wf1[k][n], 256x352
    int n = idx / K3, k = idx - n * K3;
    float v = (k < KM) ? Wf1[(size_t)k * FFN_H + n] : 0.f;
    Wf1bT[idx] = __float2bfloat16(v);
  }
}

// ---------------- atom_output f32 -> bf16 (halves gather traffic) ----------------
__global__ void conv_ao_kernel(const float* __restrict__ ao, bf16* __restrict__ ao16) {
  const int idx = blockIdx.x * 256 + threadIdx.x;   // exactly N_ATOMS*HID/8 threads
  const float4 v0 = *(const float4*)&ao[(size_t)idx * 8];
  const float4 v1 = *(const float4*)&ao[(size_t)idx * 8 + 4];
  union { bf16 h[8]; uint4 u; } pk;
  pk.h[0] = __float2bfloat16(v0.x); pk.h[1] = __float2bfloat16(v0.y);
  pk.h[2] = __float2bfloat16(v0.z); pk.h[3] = __float2bfloat16(v0.w);
  pk.h[4] = __float2bfloat16(v1.x); pk.h[5] = __float2bfloat16(v1.y);
  pk.h[6] = __float2bfloat16(v1.z); pk.h[7] = __float2bfloat16(v1.w);
  *(uint4*)&ao16[(size_t)idx * 8] = pk.u;
}

// ---------------- fused gather + GEMM1(relu) + GEMM2 + LayerNorm ----------------
__global__ __launch_bounds__(512)
void atoms_kernel(const float* __restrict__ atom_output,
                  const bf16* __restrict__ ao16, const int use16,
                  const float* __restrict__ f_atoms,
                  const int* __restrict__ a2a,
                  const bf16* __restrict__ W1bT,
                  const float* __restrict__ b1,
                  const bf16* __restrict__ W2bT,
                  const float* __restrict__ b2,
                  const float* __restrict__ gamma,
                  const float* __restrict__ beta,
                  bf16* __restrict__ atom_emb) {
  __shared__ char smem[MT * XS * 2 + MT * HS * 2];   // 18944 + 33280 = 52224 B
  bf16* Xs = (bf16*)smem;                 // [MT][XS]  cols: 0..127 aggr, 128..278 f_atoms, 279..287 pad
  bf16* Hs = (bf16*)(smem + MT * XS * 2); // [MT][HS]
  float* Fs = (float*)smem;               // [MT][FS] aliases Xs (dead after GEMM1)

  const int tid = threadIdx.x;
  const int m0 = blockIdx.x * MT;
  const int lane = tid & 63;
  const int w = tid >> 6;
  const int lr = lane & 15;
  const int lk = lane >> 4;

  // ---- neighbor gather-sum -> Xs[:, 0:128], fully vectorized: thread = (row, 8-col group)
  {
    const int r = tid >> 4, c8 = tid & 15;
    const int arow = m0 + r;
    float s[8];
#pragma unroll
    for (int e = 0; e < 8; ++e) s[e] = 0.f;
    if (use16) {
#pragma unroll
      for (int j = 0; j < N_NBR; ++j) {
        const int nb = a2a[arow * N_NBR + j];
        const uint4 u = *(const uint4*)&ao16[(size_t)nb * HID + c8 * 8];
        s[0] += blo(u.x); s[1] += bhi(u.x);
        s[2] += blo(u.y); s[3] += bhi(u.y);
        s[4] += blo(u.z); s[5] += bhi(u.z);
        s[6] += blo(u.w); s[7] += bhi(u.w);
      }
    } else {
#pragma unroll
      for (int j = 0; j < N_NBR; ++j) {
        const int nb = a2a[arow * N_NBR + j];
        const float* p = &atom_output[(size_t)nb * HID + c8 * 8];
        const float4 v0 = *(const float4*)p;
        const float4 v1 = *(const float4*)(p + 4);
        s[0] += v0.x; s[1] += v0.y; s[2] += v0.z; s[3] += v0.w;
        s[4] += v1.x; s[5] += v1.y; s[6] += v1.z; s[7] += v1.w;
      }
    }
    union { bf16 h[8]; uint4 u; } pk;
#pragma unroll
    for (int e = 0; e < 8; ++e) pk.h[e] = __float2bfloat16(s[e]);
    *(uint4*)&Xs[r * XS + c8 * 8] = pk.u;
  }

  // ---- f_atoms -> Xs[:, 128:279]  (tile is contiguous in HBM: flat float4 loads)
  for (int q = tid; q < (MT * FDIM) / 4; q += 512) {   // 1208 float4s
    const float4 v = *(const float4*)&f_atoms[(size_t)m0 * FDIM + q * 4];
    const float vf[4] = { v.x, v.y, v.z, v.w };
#pragma unroll
    for (int e = 0; e < 4; ++e) {
      const int flat = q * 4 + e;
      const int rr = flat / FDIM, cc = flat - rr * FDIM;
      Xs[rr * XS + HID + cc] = __float2bfloat16(vf[e]);
    }
  }
  // ---- zero K-pad cols 279..287
  if (tid < MT * (K1P - KX)) {
    const int rr = tid / (K1P - KX), cc = tid - rr * (K1P - KX);
    Xs[rr * XS + KX + cc] = __float2bfloat16(0.f);
  }
  __syncthreads();

  // ---- GEMM1: Xs[32 x 288] @ W1[288 x 512] -> relu -> Hs (bf16), output computed transposed D[n][m]
  {
    const int wn = w * 64;
    f32x4 acc[2][4];
#pragma unroll
    for (int mi = 0; mi < 2; ++mi)
#pragma unroll
      for (int ni = 0; ni < 4; ++ni) acc[mi][ni] = (f32x4)0.f;
#pragma unroll 3
    for (int kk = 0; kk < K1P / 32; ++kk) {
      bf16x8 a[2], b[4];
#pragma unroll
      for (int mi = 0; mi < 2; ++mi)
        a[mi] = *(const bf16x8*)&Xs[(mi * 16 + lr) * XS + kk * 32 + lk * 8];
#pragma unroll
      for (int ni = 0; ni < 4; ++ni)
        b[ni] = *(const bf16x8*)&W1bT[(size_t)(wn + ni * 16 + lr) * K1P + kk * 32 + lk * 8];
#pragma unroll
      for (int mi = 0; mi < 2; ++mi)
#pragma unroll
        for (int ni = 0; ni < 4; ++ni)   // swapped operands: D row index = n, col index = m
          acc[mi][ni] = __builtin_amdgcn_mfma_f32_16x16x32_bf16(b[ni], a[mi], acc[mi][ni], 0, 0, 0);
    }
    // lane holds n = wn+ni*16+lk*4+{0..3}, m = mi*16+lr  -> 4 consecutive n: pack, ds_write_b64
#pragma unroll
    for (int ni = 0; ni < 4; ++ni) {
      const int nb4 = wn + ni * 16 + lk * 4;
      const float4 bb = *(const float4*)&b1[nb4];
      const float bbf[4] = { bb.x, bb.y, bb.z, bb.w };
#pragma unroll
      for (int mi = 0; mi < 2; ++mi) {
        union { bf16 h[4]; uint2 u2; } pk;
#pragma unroll
        for (int r = 0; r < 4; ++r) {
          const float h = acc[mi][ni][r] + bbf[r];
          pk.h[r] = __float2bfloat16(h > 0.f ? h : 0.f);
        }
        *(uint2*)&Hs[(mi * 16 + lr) * HS + nb4] = pk.u2;
      }
    }
  }
  __syncthreads();

  // ---- GEMM2: Hs[32 x 512] @ W2[512 x 128] -> +b2 -> Fs (f32)
  {
    const int n2 = w * 16 + lr;
    f32x4 acc2[2];
    acc2[0] = (f32x4)0.f; acc2[1] = (f32x4)0.f;
#pragma unroll 4
    for (int kk = 0; kk < DFF / 32; ++kk) {
      const bf16x8 bfrag = *(const bf16x8*)&W2bT[(size_t)n2 * DFF + kk * 32 + lk * 8];
#pragma unroll
      for (int mi = 0; mi < 2; ++mi) {
        const bf16x8 afrag = *(const bf16x8*)&Hs[(mi * 16 + lr) * HS + kk * 32 + lk * 8];
        acc2[mi] = __builtin_amdgcn_mfma_f32_16x16x32_bf16(afrag, bfrag, acc2[mi], 0, 0, 0);
      }
    }
    const float bias2 = b2[n2];
#pragma unroll
    for (int mi = 0; mi < 2; ++mi)
#pragma unroll
      for (int r = 0; r < 4; ++r) {
        const int row = mi * 16 + lk * 4 + r;
        Fs[row * FS + n2] = acc2[mi][r] + bias2;
      }
  }
  __syncthreads();

  // ---- LayerNorm each of MT rows, write atom_emb bf16
  {
#pragma unroll
    for (int i = 0; i < MT / 8; ++i) {
      const int row = w * (MT / 8) + i;
      const float x0 = Fs[row * FS + lane];
      const float x1 = Fs[row * FS + 64 + lane];
      float s = x0 + x1;
      float q = x0 * x0 + x1 * x1;
#pragma unroll
      for (int off = 32; off > 0; off >>= 1) {
        s += __shfl_xor(s, off);
        q += __shfl_xor(q, off);
      }
      const float mu = s * (1.f / 128.f);
      const float var = q * (1.f / 128.f) - mu * mu;
      const float rs = rsqrtf(var + 1e-6f);
      const int atom = m0 + row;
      atom_emb[(size_t)atom * HID + lane] =
          __float2bfloat16(gamma[lane] * ((x0 - mu) * rs) + beta[lane]);
      atom_emb[(size_t)atom * HID + 64 + lane] =
          __float2bfloat16(gamma[64 + lane] * ((x1 - mu) * rs) + beta[64 + lane]);
    }
  }
}

// ---------------- segment mean + concat features -> mol_cat bf16 (K-padded) ----------------
__global__ void mol_kernel(const bf16* __restrict__ atom_emb,
                           const float* __restrict__ features,
                           const int* __restrict__ a_scope,
                           bf16* __restrict__ mol_cat) {
  const int m = blockIdx.x;
  const int tid = threadIdx.x;   // 128 threads
  const int start = a_scope[2 * m];
  const int size  = a_scope[2 * m + 1];
  float s = 0.f;
  for (int a = start; a < start + size; ++a)
    s += bf2f(atom_emb[(size_t)a * HID + tid]);
  mol_cat[(size_t)m * K3 + tid] = __float2bfloat16(s / (float)size);
  for (int c = tid; c < FEAT; c += 128)
    mol_cat[(size_t)m * K3 + HID + c] = __float2bfloat16(features[(size_t)m * FEAT + c]);
  for (int c = KM + tid; c < K3; c += 128)
    mol_cat[(size_t)m * K3 + c] = __float2bfloat16(0.f);
}

// ---------------- mol FFN layer 1: [8000 x 352] @ [352 x 256] relu ----------------
__global__ __launch_bounds__(512)
void molffn1_kernel(const bf16* __restrict__ mol_cat,
                    const bf16* __restrict__ Wf1bT,
                    const float* __restrict__ bf1,
                    bf16* __restrict__ Hf) {
  __shared__ bf16 As[64 * MS];   // 45 KB
  const int tid = threadIdx.x;
  const int m0 = blockIdx.x * 64;
  for (int idx = tid; idx < 64 * (K3 / 8); idx += 512) {
    int r = idx / (K3 / 8), qv = idx - r * (K3 / 8);
    *(uint4*)&As[r * MS + qv * 8] = *(const uint4*)&mol_cat[(size_t)(m0 + r) * K3 + qv * 8];
  }
  __syncthreads();
  const int lane = tid & 63, w = tid >> 6;
  const int lr = lane & 15, lk = lane >> 4;
  const int wn = w * 32;
  f32x4 acc[4][2];
#pragma unroll
  for (int mi = 0; mi < 4; ++mi)
#pragma unroll
    for (int ni = 0; ni < 2; ++ni) acc[mi][ni] = (f32x4)0.f;
#pragma unroll 3
  for (int kk = 0; kk < K3 / 32; ++kk) {
    bf16x8 a[4], b[2];
#pragma unroll
    for (int mi = 0; mi < 4; ++mi)
      a[mi] = *(const bf16x8*)&As[(mi * 16 + lr) * MS + kk * 32 + lk * 8];
#pragma unroll
    for (int ni = 0; ni < 2; ++ni)
      b[ni] = *(const bf16x8*)&Wf1bT[(size_t)(wn + ni * 16 + lr) * K3 + kk * 32 + lk * 8];
#pragma unroll
    for (int mi = 0; mi < 4; ++mi)
#pragma unroll
      for (int ni = 0; ni < 2; ++ni)
        acc[mi][ni] = __builtin_amdgcn_mfma_f32_16x16x32_bf16(a[mi], b[ni], acc[mi][ni], 0, 0, 0);
  }
#pragma unroll
  for (int ni = 0; ni < 2; ++ni) {
    const int n = wn + ni * 16 + lr;
    const float bias = bf1[n];
#pragma unroll
    for (int mi = 0; mi < 4; ++mi)
#pragma unroll
      for (int r = 0; r < 4; ++r) {
        const int row = mi * 16 + lk * 4 + r;
        const float h = acc[mi][ni][r] + bias;
        Hf[(size_t)(m0 + row) * FFN_H + n] = __float2bfloat16(h > 0.f ? h : 0.f);
      }
  }
}

// ---------------- mol FFN layer 2: [8000 x 256] @ [256 x 12] ----------------
__global__ void molffn2_kernel(const bf16* __restrict__ Hf,
                               const float* __restrict__ Wf2,
                               const float* __restrict__ bias2,
                               float* __restrict__ out) {
  const int gid = blockIdx.x * 256 + threadIdx.x;  // exactly 96000 threads
  const int m = gid / TASKS, t = gid - m * TASKS;
  float s = bias2[t];
  for (int k = 0; k < FFN_H; ++k)
    s += bf2f(Hf[(size_t)m * FFN_H + k]) * Wf2[k * TASKS + t];
  out[gid] = s;
}

extern "C" void kernel_launch(void* const* d_in, const int* in_sizes, int n_in,
                              void* d_out, int out_size, void* d_ws, size_t ws_size,
                              hipStream_t stream) {
  const float* atom_output = (const float*)d_in[0];
  const float* f_atoms     = (const float*)d_in[1];
  const float* features    = (const float*)d_in[2];
  const int*   a2a         = (const int*)d_in[3];
  const int*   a_scope     = (const int*)d_in[4];
  const float* W1   = (const float*)d_in[5];
  const float* b1   = (const float*)d_in[6];
  const float* W2   = (const float*)d_in[7];
  const float* b2   = (const float*)d_in[8];
  const float* gamma = (const float*)d_in[9];
  const float* beta  = (const float*)d_in[10];
  const float* Wf1  = (const float*)d_in[11];
  const float* bf1  = (const float*)d_in[12];
  const float* Wf2  = (const float*)d_in[13];
  const float* bf2v = (const float*)d_in[14];
  float* out = (float*)d_out;

  char* ws = (char*)d_ws;
  size_t off = 0;
  bf16* W1bT  = (bf16*)(ws + off); off += (size_t)DFF * K1P * 2;     // 294912
  bf16* W2bT  = (bf16*)(ws + off); off += (size_t)HID * DFF * 2;     // 131072
  bf16* Wf1bT = (bf16*)(ws + off); off += (size_t)FFN_H * K3 * 2;    // 180224
  bf16* atom_emb = (bf16*)(ws + off); off += (size_t)N_ATOMS * HID * 2; // 51.2 MB
  bf16* mol_cat  = (bf16*)(ws + off); off += (size_t)N_MOLS * K3 * 2;   // 5.6 MB
  bf16* Hf       = (bf16*)(ws + off); off += (size_t)N_MOLS * FFN_H * 2;// 4.1 MB
  bf16* ao16     = (bf16*)(ws + off); off += (size_t)N_ATOMS * HID * 2; // 51.2 MB (optional)
  const int use16 = (ws_size >= off) ? 1 : 0;

  hipLaunchKernelGGL(prep_weights_kernel, dim3(1184), dim3(256), 0, stream,
                     W1, W2, Wf1, W1bT, W2bT, Wf1bT);
  if (use16)
    hipLaunchKernelGGL(conv_ao_kernel, dim3(N_ATOMS * HID / 8 / 256), dim3(256), 0, stream,
                       atom_output, ao16);
  hipLaunchKernelGGL(atoms_kernel, dim3(N_ATOMS / MT), dim3(512), 0, stream,
                     atom_output, ao16, use16, f_atoms, a2a,
                     W1bT, b1, W2bT, b2, gamma, beta, atom_emb);
  hipLaunchKernelGGL(mol_kernel, dim3(N_MOLS), dim3(128), 0, stream,
                     atom_emb, features, a_scope, mol_cat);
  hipLaunchKernelGGL(molffn1_kernel, dim3(N_MOLS / 64), dim3(512), 0, stream,
                     mol_cat, Wf1bT, bf1, Hf);
  hipLaunchKernelGGL(molffn2_kernel, dim3(N_MOLS * TASKS / 256), dim3(256), 0, stream,
                     Hf, Wf2, bf2v, out);
}